// Round 1
// baseline (54.336 us; speedup 1.0000x reference)
//
#include <hip/hip_runtime.h>
#include <hip/hip_bf16.h>
#include <math.h>

// Problem constants
#define S_LEN 16384
#define E_DIM 2048
#define H_DIM 1024
#define G_DIM 4096   // 4*H
#define C_DIM 5

#define RCH 128                       // row chunks for column-sum phase 1
#define ROWS_PER_CHUNK (S_LEN / RCH)  // 128

// workspace layout (float offsets)
#define WS_PART   0                              // RCH*E_DIM = 262144 floats (1 MB)
#define WS_COLSUM (WS_PART + RCH * E_DIM)        // 2048
#define WS_G0     (WS_COLSUM + E_DIM)            // 4096
#define WS_H1     (WS_G0 + G_DIM)                // 1024
#define WS_G1     (WS_H1 + H_DIM)                // 4096
#define WS_H2     (WS_G1 + G_DIM)                // 1024
// total ~ 274k floats ~= 1.1 MB

// ---------------------------------------------------------------------------
// Phase 1: per-row-chunk partial column sums of encoder_hiddens (S x E).
// grid = 2 colgroups x RCH chunks = 256 blocks, 256 threads, float4 per thread.
__global__ __launch_bounds__(256) void colsum_partial_k(
    const float4* __restrict__ enc, float4* __restrict__ part) {
  const int E4 = E_DIM / 4;  // 512
  int colgroup = blockIdx.x & 1;
  int chunk = blockIdx.x >> 1;
  int e4 = colgroup * 256 + threadIdx.x;  // 0..511
  float4 acc = {0.f, 0.f, 0.f, 0.f};
  int r0 = chunk * ROWS_PER_CHUNK;
#pragma unroll 4
  for (int r = r0; r < r0 + ROWS_PER_CHUNK; ++r) {
    float4 v = enc[(size_t)r * E4 + e4];
    acc.x += v.x; acc.y += v.y; acc.z += v.z; acc.w += v.w;
  }
  part[chunk * E4 + e4] = acc;
}

// Phase 2: reduce the RCH partials -> colsum (deterministic order).
__global__ __launch_bounds__(256) void colsum_final_k(
    const float4* __restrict__ part, float4* __restrict__ colsum) {
  const int E4 = E_DIM / 4;  // 512
  int e4 = blockIdx.x * blockDim.x + threadIdx.x;  // 0..511
  if (e4 >= E4) return;
  float4 acc = {0.f, 0.f, 0.f, 0.f};
  for (int ch = 0; ch < RCH; ++ch) {
    float4 v = part[ch * E4 + e4];
    acc.x += v.x; acc.y += v.y; acc.z += v.z; acc.w += v.w;
  }
  colsum[e4] = acc;
}

// ---------------------------------------------------------------------------
// LSTM gate matvec: gates[row] = w_ih[row,:]*x + b_ih[row] + w_hh[row,:]*h + b_hh[row]
// One wave (64 lanes) per row; 4 waves per block; grid = G_DIM/4 blocks.
__global__ __launch_bounds__(256) void gates_k(
    const float4* __restrict__ w_ih, const float4* __restrict__ w_hh,
    const float* __restrict__ b_ih, const float* __restrict__ b_hh,
    const float4* __restrict__ x, int xlen4,
    const float4* __restrict__ h, int hlen4,
    float* __restrict__ gates) {
  int wave = threadIdx.x >> 6;
  int lane = threadIdx.x & 63;
  int row = blockIdx.x * 4 + wave;  // < G_DIM

  float acc = 0.f;
  const float4* wi = w_ih + (size_t)row * xlen4;
  for (int k = lane; k < xlen4; k += 64) {
    float4 w4 = wi[k];
    float4 v = x[k];
    acc += w4.x * v.x + w4.y * v.y + w4.z * v.z + w4.w * v.w;
  }
  const float4* wh = w_hh + (size_t)row * hlen4;
  for (int k = lane; k < hlen4; k += 64) {
    float4 w4 = wh[k];
    float4 v = h[k];
    acc += w4.x * v.x + w4.y * v.y + w4.z * v.z + w4.w * v.w;
  }
#pragma unroll
  for (int off = 32; off > 0; off >>= 1) acc += __shfl_down(acc, off);
  if (lane == 0) gates[row] = acc + b_ih[row] + b_hh[row];
}

// ---------------------------------------------------------------------------
// LSTM cell elementwise: gate order i, f, g, o. Only h_out is needed downstream.
__global__ __launch_bounds__(256) void cell_k(
    const float* __restrict__ gates, const float* __restrict__ c_prev,
    float* __restrict__ h_out) {
  int j = blockIdx.x * blockDim.x + threadIdx.x;  // < H_DIM
  if (j >= H_DIM) return;
  float ig = gates[j];
  float fg = gates[H_DIM + j];
  float gg = gates[2 * H_DIM + j];
  float og = gates[3 * H_DIM + j];
  float si = 1.f / (1.f + expf(-ig));
  float sf = 1.f / (1.f + expf(-fg));
  float so = 1.f / (1.f + expf(-og));
  float c2 = sf * c_prev[j] + si * tanhf(gg);
  h_out[j] = so * tanhf(c2);
}

// ---------------------------------------------------------------------------
// Final FC: out[k] = fc_w[k,:]*h2 + fc_b[k]. One wave per output row, 5 waves.
__global__ __launch_bounds__(320) void fc_k(
    const float4* __restrict__ fc_w, const float* __restrict__ fc_b,
    const float4* __restrict__ h2, float* __restrict__ out) {
  int wave = threadIdx.x >> 6;
  int lane = threadIdx.x & 63;
  if (wave >= C_DIM) return;
  const int H4 = H_DIM / 4;  // 256
  float acc = 0.f;
  const float4* wr = fc_w + (size_t)wave * H4;
  for (int k = lane; k < H4; k += 64) {
    float4 w4 = wr[k];
    float4 v = h2[k];
    acc += w4.x * v.x + w4.y * v.y + w4.z * v.z + w4.w * v.w;
  }
#pragma unroll
  for (int off = 32; off > 0; off >>= 1) acc += __shfl_down(acc, off);
  if (lane == 0) out[wave] = acc + fc_b[wave];
}

// ---------------------------------------------------------------------------
extern "C" void kernel_launch(void* const* d_in, const int* in_sizes, int n_in,
                              void* d_out, int out_size, void* d_ws, size_t ws_size,
                              hipStream_t stream) {
  const float* enc     = (const float*)d_in[0];   // (S,1,E)
  const float* hidden  = (const float*)d_in[1];   // (2,1,H)
  const float* c_in    = (const float*)d_in[2];   // (2,1,H)
  // d_in[3] attn_w, d_in[4] attn_b: dead code (softmax over size-1 axis == 1)
  const float* w_ih_l0 = (const float*)d_in[5];   // (4H, E)
  const float* w_hh_l0 = (const float*)d_in[6];   // (4H, H)
  const float* b_ih_l0 = (const float*)d_in[7];
  const float* b_hh_l0 = (const float*)d_in[8];
  const float* w_ih_l1 = (const float*)d_in[9];   // (4H, H)
  const float* w_hh_l1 = (const float*)d_in[10];  // (4H, H)
  const float* b_ih_l1 = (const float*)d_in[11];
  const float* b_hh_l1 = (const float*)d_in[12];
  const float* fc_w    = (const float*)d_in[13];  // (C, H)
  const float* fc_b    = (const float*)d_in[14];

  float* ws = (float*)d_ws;
  float* part   = ws + WS_PART;
  float* colsum = ws + WS_COLSUM;
  float* g0     = ws + WS_G0;
  float* h1     = ws + WS_H1;
  float* g1     = ws + WS_G1;
  float* h2     = ws + WS_H2;
  float* out    = (float*)d_out;

  // 1. attn_applied = column sum of encoder_hiddens (softmax over size-1 axis == 1)
  colsum_partial_k<<<2 * RCH, 256, 0, stream>>>((const float4*)enc, (float4*)part);
  colsum_final_k<<<2, 256, 0, stream>>>((const float4*)part, (float4*)colsum);

  // 2. LSTM layer 0: x = colsum (E), h = hidden[0], c = c[0]
  gates_k<<<G_DIM / 4, 256, 0, stream>>>(
      (const float4*)w_ih_l0, (const float4*)w_hh_l0, b_ih_l0, b_hh_l0,
      (const float4*)colsum, E_DIM / 4, (const float4*)hidden, H_DIM / 4, g0);
  cell_k<<<H_DIM / 256, 256, 0, stream>>>(g0, c_in, h1);

  // 3. LSTM layer 1: x = h1, h = hidden[1], c = c[1]
  gates_k<<<G_DIM / 4, 256, 0, stream>>>(
      (const float4*)w_ih_l1, (const float4*)w_hh_l1, b_ih_l1, b_hh_l1,
      (const float4*)h1, H_DIM / 4, (const float4*)(hidden + H_DIM), H_DIM / 4, g1);
  cell_k<<<H_DIM / 256, 256, 0, stream>>>(g1, c_in + H_DIM, h2);

  // 4. out = h2 @ fc_w.T + fc_b
  fc_k<<<1, 320, 0, stream>>>((const float4*)fc_w, fc_b, (const float4*)h2, out);
}